// Round 8
// baseline (166.601 us; speedup 1.0000x reference)
//
#include <hip/hip_runtime.h>
#include <cfloat>
#include <cmath>

#define NP 10000
#define NG 1000
#define NC 80
#define LMAX 6
#define NCH 4
#define CHSZ (NP / NCH)     // 2500 preds per wave-task
#define WMAIN 39            // 39*64 = 2496
#define WTAIL 4             // + 4 = 2500

#define S_MULTI 12
#define S_BODY  16
#define RI_BIG  0x3fffffff
#define KMAX    0xFFFFFFFFFFFFFFFFull

// packkey(50.0f,0): strong (inb) costs < ~28, non-strong >= ~59 (validated
// R1/R2/R6/R7 at multiple chunk sizes; argument is chunk-size-independent).
// If the chunk's 5th-smallest candidate key >= TKEY we cannot prove coverage
// of the chunk's true top-5 -> exact chunk scan.
#define TKEY    0xC248000000000000ull

// per-wave candidate region (LDS ints): 4 waves x 768.
// Expected hits/wave ~100 (4% x 2500), big-gt ~500; overflow -> exact scan.
#define WCAP    768

__device__ __forceinline__ bool lexless(float av, int ai, float bv, int bi) {
    return (av < bv) || (av == bv && ai < bi);
}

// float -> order-preserving u32 (no NaNs in this data), packed with index.
// ascending u64 order == lexicographic (value asc, index asc).
__device__ __forceinline__ unsigned long long packkey(float v, int idx) {
    unsigned u = __float_as_uint(v);
    u ^= (unsigned)(((int)u) >> 31) | 0x80000000u;
    return ((unsigned long long)u << 32) | (unsigned)idx;
}
__device__ __forceinline__ int keyidx(unsigned long long k) {
    return (int)(unsigned)(k & 0xFFFFFFFFu);
}

// Exact sequential +1e5 inflation (reference adds 1e5 once per loop iter).
__device__ __forceinline__ float inflate(float c, int k) {
    for (int q = 0; q < k; q++) c += 100000.0f;
    return c;
}

// Per-pair cost+iou from precomputed tables. Contraction OFF so every kernel
// that recomputes cost(i,j) agrees bit-exactly.
__device__ __forceinline__ void cost_iou(float4 p, float4 pn, float4 pi,
        float4 g, float4 cb, float4 Gn, float ga, float clsv,
        float& cc_out, float& iou_out) {
#pragma clang fp contract(off)
    float wx = fminf(p.z, g.z) - fmaxf(p.x, g.x); wx = fmaxf(wx, 0.0f);
    float wy = fminf(p.w, g.w) - fmaxf(p.y, g.y); wy = fmaxf(wy, 0.0f);
    float inter = wx * wy;
    float uni = pi.z + ga - inter;
    float iou = inter / fmaxf(uni, 1e-12f);
    float ex = fmaxf(p.z, g.z) - fminf(p.x, g.x); ex = fmaxf(ex, 0.0f);
    float ey = fmaxf(p.w, g.w) - fminf(p.y, g.y); ey = fmaxf(ey, 0.0f);
    float enc = ex * ey;
    float giou = iou - (enc - uni) / fmaxf(enc, 1e-12f);
    float l1 = ((fabsf(pn.x - Gn.x) + fabsf(pn.y - Gn.y))
                + fabsf(pn.z - Gn.z)) + fabsf(pn.w - Gn.w);
    float cc = clsv + l1 * 5.0f;
    cc = cc + (-giou * 2.0f);
    bool inb = (pi.x > g.x && pi.x < g.z && pi.y > g.y && pi.y < g.w);
    bool inc = (pi.x > cb.x && pi.x < cb.z && pi.y > cb.y && pi.y < cb.w);
    cc = cc + ((inb && inc) ? 0.0f : 100.0f);
    cc = cc + pi.w;
    cc_out = cc; iou_out = iou;
}

// Proven per-lane sorted top-5 insertion (static indices after unroll).
// Per-lane top-5 is ALWAYS sufficient for the wave top-5.
__device__ __forceinline__ void ins5k(unsigned long long* kv,
        unsigned long long key) {
    if (key < kv[4]) {
        kv[4] = key;
#pragma unroll
        for (int t = 4; t > 0; t--)
            if (kv[t] < kv[t-1]) { unsigned long long tv = kv[t]; kv[t] = kv[t-1]; kv[t-1] = tv; }
    }
}
__device__ __forceinline__ void ins5i(float* iv, float iou) {
    if (iou > iv[4]) {
        iv[4] = iou;
#pragma unroll
        for (int t = 4; t > 0; t--)
            if (iv[t] > iv[t-1]) { float tv = iv[t]; iv[t] = iv[t-1]; iv[t-1] = tv; }
    }
}

// static 9-comparator sorting networks for 5 elements (constant indices only)
__device__ __forceinline__ void cswapk(unsigned long long& a,
        unsigned long long& b) {
    unsigned long long lo = (a < b) ? a : b;
    unsigned long long hi = (a < b) ? b : a;
    a = lo; b = hi;
}
__device__ __forceinline__ void sort5k(unsigned long long* a) {   // ascending
    cswapk(a[0],a[1]); cswapk(a[3],a[4]); cswapk(a[2],a[4]);
    cswapk(a[2],a[3]); cswapk(a[1],a[4]); cswapk(a[0],a[3]);
    cswapk(a[0],a[2]); cswapk(a[1],a[3]); cswapk(a[1],a[2]);
}
__device__ __forceinline__ void cswapi(float& a, float& b) {      // a=max
    float hi = fmaxf(a, b), lo = fminf(a, b);
    a = hi; b = lo;
}
__device__ __forceinline__ void sort5i(float* a) {                // descending
    cswapi(a[0],a[1]); cswapi(a[3],a[4]); cswapi(a[2],a[4]);
    cswapi(a[2],a[3]); cswapi(a[1],a[4]); cswapi(a[0],a[3]);
    cswapi(a[0],a[2]); cswapi(a[1],a[3]); cswapi(a[1],a[2]);
}

// 6-round butterfly allreduce of sorted 5-lists across the 64-lane wave.
// Bitonic partner trick: A asc ++ reverse(B asc) is bitonic; elementwise
// min(A[i], B[4-i]) yields the 5 smallest of the union (bitonic), then the
// static 5-sort restores order. Groups merged per round are disjoint ->
// each candidate contributes exactly once (multiset-correct for ious).
// After 6 rounds every lane holds the wave's exact top-5 (wave-uniform).
__device__ __forceinline__ void wavemerge5(unsigned long long* kv, float* iv) {
#pragma unroll
    for (int d = 1; d < 64; d <<= 1) {
        unsigned long long r0 = __shfl_xor(kv[0], d);
        unsigned long long r1 = __shfl_xor(kv[1], d);
        unsigned long long r2 = __shfl_xor(kv[2], d);
        unsigned long long r3 = __shfl_xor(kv[3], d);
        unsigned long long r4 = __shfl_xor(kv[4], d);
        kv[0] = (kv[0] < r4) ? kv[0] : r4;
        kv[1] = (kv[1] < r3) ? kv[1] : r3;
        kv[2] = (kv[2] < r2) ? kv[2] : r2;
        kv[3] = (kv[3] < r1) ? kv[3] : r1;
        kv[4] = (kv[4] < r0) ? kv[4] : r0;
        sort5k(kv);
        float s0 = __shfl_xor(iv[0], d);
        float s1 = __shfl_xor(iv[1], d);
        float s2 = __shfl_xor(iv[2], d);
        float s3 = __shfl_xor(iv[3], d);
        float s4 = __shfl_xor(iv[4], d);
        iv[0] = fmaxf(iv[0], s4);
        iv[1] = fmaxf(iv[1], s3);
        iv[2] = fmaxf(iv[2], s2);
        iv[3] = fmaxf(iv[3], s1);
        iv[4] = fmaxf(iv[4], s0);
        sort5i(iv);
    }
}

// ---------------------------------------------------------------------------
// Fused prep (verbatim R1). Block ranges:
//  [0,40): init state; [40,197): cls table; [197,201): per-gt tables;
//  [201,2701): wave-per-pred validity + per-pred tables
// ---------------------------------------------------------------------------
#define CLS_TI 64
#define PB_CLS0 40
#define PB_G0   197
#define PB_V0   201
__global__ __launch_bounds__(256) void k_prep(const float* __restrict__ logits,
        const float* __restrict__ pb, const float* __restrict__ gb,
        const int* __restrict__ imgw, const int* __restrict__ imgh,
        float* __restrict__ clsval, float4* __restrict__ pnorm,
        float4* __restrict__ pinfo, float4* __restrict__ gcb,
        float4* __restrict__ gnm, float* __restrict__ gar,
        int* rowcnt, int* rowfirst, int* rowiter, int* prior, int* priorcol,
        int* colsum, int* scal)
{
    __shared__ float sl[CLS_TI * (NC + 1)];
    int b = blockIdx.x;
    if (b < PB_CLS0) {
        int i = b * 256 + threadIdx.x;
        if (i < NP) {
            rowcnt[i] = 0; rowfirst[i] = 0x7fffffff; rowiter[i] = RI_BIG;
            prior[i] = 0; priorcol[i] = 0;
        }
        if (i < NG) colsum[i] = 0;
        if (i < 32) scal[i] = 0;
    } else if (b < PB_G0) {
        int i0 = (b - PB_CLS0) * CLS_TI;
        bool full = (i0 + CLS_TI) <= NP;
        if (full) {
            const float* src = logits + (size_t)i0 * NC;
            for (int e = threadIdx.x; e < CLS_TI * NC; e += 256) {
                int di = e / NC, c = e - di * NC;
                sl[di * (NC + 1) + c] = src[e];
            }
        } else {
            for (int e = threadIdx.x; e < CLS_TI * NC; e += 256) {
                int di = e / NC, c = e - di * NC;
                int i = i0 + di;
                sl[di * (NC + 1) + c] = (i < NP) ? logits[(size_t)i * NC + c] : 0.0f;
            }
        }
        __syncthreads();
        for (int e = threadIdx.x; e < CLS_TI * NC; e += 256) {
            int c = e >> 6, di = e & 63;
            int i = i0 + di;
            if (i >= NP) continue;
            float x = sl[di * (NC + 1) + c];
            float p = 1.0f / (1.0f + expf(-x));
            float neg = -log1pf(-(p - 1e-12f)) * 0.75f * (p * p);
            float om = 1.0f - p;
            float pos = -logf(p + 1e-12f) * 0.25f * (om * om);
            clsval[(size_t)c * NP + i] = (pos - neg) * 2.0f;   // * CLS_W
        }
    } else if (b < PB_V0) {
#pragma clang fp contract(off)
        int j = (b - PB_G0) * 256 + threadIdx.x;
        if (j < NG) {
            float fw = (float)imgw[0], fh = (float)imgh[0];
            float4 g = ((const float4*)gb)[j];
            float gcx = (g.x + g.z) * 0.5f, gcy = (g.y + g.w) * 0.5f;
            float gw = g.z - g.x, gh = g.w - g.y;
            float4 cb; cb.x = gcx - 2.5f * gw; cb.y = gcy - 2.5f * gh;
            cb.z = gcx + 2.5f * gw; cb.w = gcy + 2.5f * gh;
            gcb[j] = cb;
            float4 Gn; Gn.x = g.x / fw; Gn.y = g.y / fh; Gn.z = g.z / fw; Gn.w = g.w / fh;
            gnm[j] = Gn;
            gar[j] = (g.z - g.x) * (g.w - g.y);
        }
    } else {
#pragma clang fp contract(off)
        int wave = threadIdx.x >> 6;
        int lane = threadIdx.x & 63;
        int i = (b - PB_V0) * 4 + wave;
        if (i >= NP) return;
        float4 p = ((const float4*)pb)[i];
        float pcx = (p.x + p.z) * 0.5f, pcy = (p.y + p.w) * 0.5f;
        int vb = 0, vc = 0;
        const float4* gb4 = (const float4*)gb;
        // valid = any(inb) | any(inc): wave-level early exit as soon as
        // the disjunction is already established (~93% exit after 1 stride).
        for (int jb = 0; jb < NG; jb += 64) {
            int j = jb + lane;
            if (j < NG) {
                float4 g = gb4[j];
                vb |= (pcx > g.x && pcx < g.z && pcy > g.y && pcy < g.w) ? 1 : 0;
                float gcx = (g.x + g.z) * 0.5f, gcy = (g.y + g.w) * 0.5f;
                float gw = g.z - g.x, gh = g.w - g.y;
                vc |= (pcx > gcx - 2.5f * gw && pcx < gcx + 2.5f * gw &&
                       pcy > gcy - 2.5f * gh && pcy < gcy + 2.5f * gh) ? 1 : 0;
            }
            if (__any(vb | vc)) break;
        }
        int any = __any(vb | vc) ? 1 : 0;
        if (lane == 0) {
            float fw = (float)imgw[0], fh = (float)imgh[0];
            float4 pn; pn.x = p.x / fw; pn.y = p.y / fh; pn.z = p.z / fw; pn.w = p.w / fh;
            pnorm[i] = pn;
            float4 pi4; pi4.x = pcx; pi4.y = pcy;
            pi4.z = (p.z - p.x) * (p.w - p.y);
            pi4.w = any ? 0.0f : 10000.0f;
            pinfo[i] = pi4;
        }
    }
}

// ---------------------------------------------------------------------------
// k_cost2: block = gt j; each WAVE independently owns chunk c = wid.
// ZERO __syncthreads, no shared merge tree (R7 post-mortem: the block-level
// barrier/tree machinery was the invariant ~50us cost).
//  Phase 1: cheap overlap scan (overlap <=> iou > 0 exactly; superset of the
//    strong set). Wave-private LDS region, wave-uniform register cursor
//    (proven R6/R7). All lanes participate every iteration (valid-flag tail)
//    so the cursor stays wave-uniform.
//  Phase 2: dense cost_iou over the wave's region; per-LANE 5-deep insertion
//    (unconditionally sufficient); 6-round butterfly shfl merge -> every
//    lane holds the wave's exact top-5 (wave-uniform).
//  Gates (proven flow, now wave-local): cursor > WCAP -> exact chunk scan;
//    merged kv[4] >= TKEY -> redo exact chunk scan (covers cnt<5).
//  IoU pads on the dense path are 0.0f == exact non-candidate iou.
//  Lane 0 writes the sorted 5-list at (j*NCH+c)*5 -- same layout as R7, so
//  the proven 4-way k_costmerge is verbatim.
// ---------------------------------------------------------------------------
__global__ __launch_bounds__(256) void k_cost2(
        const float* __restrict__ pb, const float* __restrict__ gb,
        const int* __restrict__ glab, const float* __restrict__ clsval,
        const float4* __restrict__ pnorm, const float4* __restrict__ pinfo,
        const float4* __restrict__ gcb, const float4* __restrict__ gnm,
        const float* __restrict__ gar,
        unsigned long long* __restrict__ pck, float* __restrict__ piv)
{
    __shared__ int s_list[4 * WCAP];

    int j = blockIdx.x;
    int tid = threadIdx.x;
    int wid = tid >> 6;
    int ln  = tid & 63;
    float4 g  = ((const float4*)gb)[j];
    float4 cb = gcb[j];
    float4 Gn = gnm[j];
    float  ga = gar[j];
    const float* clscol = clsval + (size_t)glab[j] * NP;
    const float4* pb4 = (const float4*)pb;
    int base_i = wid * CHSZ;

    // ---- phase 1: overlap scan, atomic-free wave-private compaction ----
    int wbase = 0;                       // wave-uniform cursor
    for (int k = 0; k <= WMAIN; k++) {
        bool valid = (k < WMAIN) | (ln < WTAIL);
        int i = base_i + ln + k * 64;
        float4 p = pb4[valid ? i : base_i];
        bool o = valid & (p.z > g.x) & (g.z > p.x) & (p.w > g.y) & (g.w > p.y);
        unsigned long long m = __ballot(o ? 1 : 0);
        if (o) {
            int slot = wbase + __popcll(m & ((1ull << ln) - 1ull));
            if (slot < WCAP) s_list[wid * WCAP + slot] = i;
        }
        wbase += __popcll(m);
    }
    int cnt = wbase;
    bool overflow = (cnt > WCAP);        // wave-uniform

    unsigned long long kv[5]; float iv[5];
#pragma unroll
    for (int t = 0; t < 5; t++) { kv[t] = KMAX; iv[t] = overflow ? -1.0f : 0.0f; }

    if (!overflow) {
        // ---- phase 2: dense evals over the wave's candidate region ----
        for (int q = ln; q < cnt; q += 64) {
            int i = s_list[wid * WCAP + q];
            float cc, iou;
            cost_iou(pb4[i], pnorm[i], pinfo[i], g, cb, Gn, ga, clscol[i], cc, iou);
            ins5k(kv, packkey(cc, i)); ins5i(iv, iou);
        }
    } else {
        // exact chunk scan (rare: wave saw > WCAP hits)
        for (int k = 0; k <= WMAIN; k++) {
            bool valid = (k < WMAIN) | (ln < WTAIL);
            if (valid) {
                int i = base_i + ln + k * 64;
                float cc, iou;
                cost_iou(pb4[i], pnorm[i], pinfo[i], g, cb, Gn, ga, clscol[i], cc, iou);
                ins5k(kv, packkey(cc, i)); ins5i(iv, iou);
            }
        }
    }
    wavemerge5(kv, iv);                  // all lanes now hold wave top-5

    // gate: wave-uniform (all lanes hold identical merged lists)
    bool redo = !overflow && (kv[4] >= TKEY);
    if (redo) {
#pragma unroll
        for (int t = 0; t < 5; t++) { kv[t] = KMAX; iv[t] = -1.0f; }
        for (int k = 0; k <= WMAIN; k++) {
            bool valid = (k < WMAIN) | (ln < WTAIL);
            if (valid) {
                int i = base_i + ln + k * 64;
                float cc, iou;
                cost_iou(pb4[i], pnorm[i], pinfo[i], g, cb, Gn, ga, clscol[i], cc, iou);
                ins5k(kv, packkey(cc, i)); ins5i(iv, iou);
            }
        }
        wavemerge5(kv, iv);
    }

    if (ln == 0) {
        int ob = (j * NCH + wid) * 5;
#pragma unroll
        for (int t = 0; t < 5; t++) { pck[ob + t] = kv[t]; piv[ob + t] = iv[t]; }
    }
}

// ---------------------------------------------------------------------------
// Merge partials (verbatim R7, proven): thread per gt, exact 4-way merge of
// sorted 5-lists; dk = trunc(sum of descending merged top-5 ious); top5
// store; row atomics.
// ---------------------------------------------------------------------------
__global__ __launch_bounds__(256) void k_costmerge(
        const unsigned long long* __restrict__ pck, const float* __restrict__ piv,
        int* __restrict__ rowcnt, int* __restrict__ rowfirst,
        int* __restrict__ rowiter, int* __restrict__ top5,
        int* __restrict__ dkarr)
{
    int j = blockIdx.x * 256 + threadIdx.x;
    if (j >= NG) return;
    int base = j * NCH * 5;
    int h0 = 0, h1 = 0, h2 = 0, h3 = 0;
    int besti[5];
#pragma unroll
    for (int r = 0; r < 5; r++) {
        unsigned long long v0 = (h0 < 5) ? pck[base + h0]      : KMAX;
        unsigned long long v1 = (h1 < 5) ? pck[base + 5 + h1]  : KMAX;
        unsigned long long v2 = (h2 < 5) ? pck[base + 10 + h2] : KMAX;
        unsigned long long v3 = (h3 < 5) ? pck[base + 15 + h3] : KMAX;
        unsigned long long best = v0; int sel = 0;
        if (v1 < best) { best = v1; sel = 1; }
        if (v2 < best) { best = v2; sel = 2; }
        if (v3 < best) { best = v3; sel = 3; }
        besti[r] = keyidx(best);
        h0 += (sel == 0); h1 += (sel == 1); h2 += (sel == 2); h3 += (sel == 3);
    }
    int g0 = 0, g1 = 0, g2 = 0, g3 = 0;
    float ivm[5];
#pragma unroll
    for (int r = 0; r < 5; r++) {
        float w0 = (g0 < 5) ? piv[base + g0]      : -2.0f;
        float w1 = (g1 < 5) ? piv[base + 5 + g1]  : -2.0f;
        float w2 = (g2 < 5) ? piv[base + 10 + g2] : -2.0f;
        float w3 = (g3 < 5) ? piv[base + 15 + g3] : -2.0f;
        float best = w0; int sel = 0;
        if (w1 > best) { best = w1; sel = 1; }
        if (w2 > best) { best = w2; sel = 2; }
        if (w3 > best) { best = w3; sel = 3; }
        ivm[r] = best;
        g0 += (sel == 0); g1 += (sel == 1); g2 += (sel == 2); g3 += (sel == 3);
    }
    float s = (((ivm[0] + ivm[1]) + ivm[2]) + ivm[3]) + ivm[4];
    int dk = (int)s;                 // astype(int32): truncation
    if (dk < 1) dk = 1;
    dkarr[j] = dk;
#pragma unroll
    for (int r = 0; r < 5; r++) top5[j * 5 + r] = besti[r];
    for (int t = 0; t < dk; t++) {
        int r = besti[t];
        atomicAdd(&rowcnt[r], 1);
        atomicMin(&rowfirst[r], j);
        atomicMin(&rowiter[r], -1);   // initially matched
    }
}

// ---------------------------------------------------------------------------
// Fused prior-detect + pfix + surv (verbatim R1).
// ---------------------------------------------------------------------------
__global__ __launch_bounds__(256) void k_pfixsurv(const float* __restrict__ pb,
        const float* __restrict__ gb, const int* __restrict__ glab,
        const float* __restrict__ clsval,
        const float4* __restrict__ pnorm, const float4* __restrict__ pinfo,
        const float4* __restrict__ gcb, const float4* __restrict__ gnm,
        const float* __restrict__ gar,
        int* __restrict__ prior, int* __restrict__ priorcol,
        int* __restrict__ colsum,
        const int* __restrict__ rowcnt, const int* __restrict__ top5,
        const int* __restrict__ dkarr)
{
    int b = blockIdx.x;
    int tid = threadIdx.x;
    if (b >= 2500) {
        int j = (b - 2500) * 256 + tid;
        if (j >= NG) return;
        int c = 0;
        int dk = dkarr[j];
        for (int t = 0; t < dk; t++) if (rowcnt[top5[j * 5 + t]] == 1) c++;
        if (c) atomicAdd(&colsum[j], c);
        return;
    }
    __shared__ float rv[256]; __shared__ int ri[256];
    for (int q = 0; q < 4; q++) {
        int row = b * 4 + q;
        if (rowcnt[row] <= 1) continue;      // uniform across block
        if (tid == 0) prior[row] = 1;
        float4 p = ((const float4*)pb)[row];
        float4 pn = pnorm[row];
        float4 pi4 = pinfo[row];
        float best = FLT_MAX; int bj = 0x7fffffff;
        for (int j = tid; j < NG; j += 256) {
            float cc, iou;
            cost_iou(p, pn, pi4, ((const float4*)gb)[j], gcb[j], gnm[j], gar[j],
                     clsval[(size_t)glab[j] * NP + row], cc, iou);
            if (lexless(cc, j, best, bj)) { best = cc; bj = j; }
        }
        rv[tid] = best; ri[tid] = bj; __syncthreads();
        for (int w = 128; w > 0; w >>= 1) {
            if (tid < w) {
                float ov = rv[tid + w]; int oi = ri[tid + w];
                if (lexless(ov, oi, rv[tid], ri[tid])) { rv[tid] = ov; ri[tid] = oi; }
            }
            __syncthreads();
        }
        if (tid == 0) {
            priorcol[row] = ri[0];
            atomicAdd(&colsum[ri[0]], 1);
        }
        __syncthreads();
    }
}

// ---------------------------------------------------------------------------
// iterB (verbatim R1): block per column; active iff colsum[j]==0.
// ---------------------------------------------------------------------------
__global__ __launch_bounds__(256) void k_iterB(const float* __restrict__ pb,
        const float* __restrict__ gb, const int* __restrict__ glab,
        const float* __restrict__ clsval,
        const float4* __restrict__ pnorm, const float4* __restrict__ pinfo,
        const float4* __restrict__ gcb, const float4* __restrict__ gnm,
        const float* __restrict__ gar, const int* __restrict__ top5,
        int* __restrict__ rowiter, int* __restrict__ rowcnt,
        int* __restrict__ rowfirst, int* __restrict__ colsum,
        int* __restrict__ scal, int t)
{
    int j = blockIdx.x;
    if (colsum[j] != 0) return;
    int tid = threadIdx.x;
    if (tid == 0) scal[S_BODY + t] = 1;

    __shared__ int s_pos;
    if (tid == 0) {
        int pos = -1;
        for (int r = 0; r < 5; r++) {
            int i = top5[j * 5 + r];
            if (rowiter[i] >= t) { pos = i; break; }
        }
        s_pos = pos;
    }
    __syncthreads();
    int pos = s_pos;

    if (pos < 0) {
        // fallback: full argmin over uninflated rows
        float4 g  = ((const float4*)gb)[j];
        float4 cb = gcb[j];
        float4 Gn = gnm[j];
        float  ga = gar[j];
        const float* clscol = clsval + (size_t)glab[j] * NP;
        const float4* pb4 = (const float4*)pb;
        __shared__ float rv[256]; __shared__ int ri[256];
        float best = FLT_MAX; int bi = 0x7fffffff;
        for (int i = tid; i < NP; i += 256) {
            if (rowiter[i] < t) continue;
            float cc, iou;
            cost_iou(pb4[i], pnorm[i], pinfo[i], g, cb, Gn, ga, clscol[i], cc, iou);
            if (lexless(cc, i, best, bi)) { best = cc; bi = i; }
        }
        rv[tid] = best; ri[tid] = bi; __syncthreads();
        for (int w = 128; w > 0; w >>= 1) {
            if (tid < w) {
                float ov = rv[tid + w]; int oi = ri[tid + w];
                if (lexless(ov, oi, rv[tid], ri[tid])) { rv[tid] = ov; ri[tid] = oi; }
            }
            __syncthreads();
        }
        pos = ri[0];
    }

    if (tid == 0) {
        colsum[j] = 1;
        int old = atomicAdd(&rowcnt[pos], 1);
        if (old >= 1) scal[S_MULTI] = 1;
        atomicMin(&rowfirst[pos], j);
        atomicMin(&rowiter[pos], t);
    }
}

// ---------------------------------------------------------------------------
// iterC (verbatim R1): iff body ran at t && anymulti: prior rows (4/block)
// re-argmin their inflated cost (exact sequential +1e5).
// ---------------------------------------------------------------------------
__global__ __launch_bounds__(256) void k_iterC(const float* __restrict__ pb,
        const float* __restrict__ gb, const int* __restrict__ glab,
        const float* __restrict__ clsval,
        const float4* __restrict__ pnorm, const float4* __restrict__ pinfo,
        const float4* __restrict__ gcb, const float4* __restrict__ gnm,
        const float* __restrict__ gar,
        const int* __restrict__ prior, const int* __restrict__ rowiter,
        int* __restrict__ priorcol, int* __restrict__ colsum,
        int* __restrict__ scal, int t)
{
    if (scal[S_BODY + t] == 0 || scal[S_MULTI] == 0) return;
    int b = blockIdx.x;
    int tid = threadIdx.x;
    __shared__ float rv[256]; __shared__ int ri[256];
    for (int q = 0; q < 4; q++) {
        int row = b * 4 + q;
        if (!prior[row]) continue;           // uniform across block
        int k = t - rowiter[row]; if (k < 0) k = 0;   // prior rows: -1 -> t+1
        float4 p = ((const float4*)pb)[row];
        float4 pn = pnorm[row];
        float4 pi4 = pinfo[row];
        float best = FLT_MAX; int bj = 0x7fffffff;
        for (int j = tid; j < NG; j += 256) {
            float cc, iou;
            cost_iou(p, pn, pi4, ((const float4*)gb)[j], gcb[j], gnm[j], gar[j],
                     clsval[(size_t)glab[j] * NP + row], cc, iou);
            float val = inflate(cc, k);
            if (lexless(val, j, best, bj)) { best = val; bj = j; }
        }
        rv[tid] = best; ri[tid] = bj; __syncthreads();
        for (int w = 128; w > 0; w >>= 1) {
            if (tid < w) {
                float ov = rv[tid + w]; int oi = ri[tid + w];
                if (lexless(ov, oi, rv[tid], ri[tid])) { rv[tid] = ov; ri[tid] = oi; }
            }
            __syncthreads();
        }
        if (tid == 0) {
            int nb = ri[0];
            int oldc = priorcol[row];
            if (nb != oldc) {
                atomicSub(&colsum[oldc], 1);
                atomicAdd(&colsum[nb], 1);
                priorcol[row] = nb;
            }
        }
        __syncthreads();
    }
}

// ---------------------------------------------------------------------------
// Final: fg = rowcnt>0; matched = priorcol (prior rows) else rowfirst. int32.
// ---------------------------------------------------------------------------
__global__ __launch_bounds__(256) void k_final(const int* __restrict__ rowcnt,
        const int* __restrict__ prior, const int* __restrict__ priorcol,
        const int* __restrict__ rowfirst, int* __restrict__ out)
{
    int i = blockIdx.x * 256 + threadIdx.x;
    if (i >= NP) return;
    int fg = rowcnt[i] > 0;
    out[i] = fg ? 1 : 0;
    out[NP + i] = fg ? (prior[i] ? priorcol[i] : rowfirst[i]) : 0;
}

extern "C" void kernel_launch(void* const* d_in, const int* in_sizes, int n_in,
                              void* d_out, int out_size, void* d_ws, size_t ws_size,
                              hipStream_t stream)
{
    (void)in_sizes; (void)n_in; (void)out_size; (void)ws_size;
    const float* logits = (const float*)d_in[0];
    const float* pboxes = (const float*)d_in[1];
    const float* gboxes = (const float*)d_in[2];
    const int*   glab   = (const int*)d_in[3];
    const int*   imgh   = (const int*)d_in[4];
    const int*   imgw   = (const int*)d_in[5];
    int* out = (int*)d_out;

    char* w = (char*)d_ws;
    float*  clsval  = (float*)(w);                    // 3,200,000
    float4* pnorm   = (float4*)(w + 3200000);         //   160,000
    float4* pinfo   = (float4*)(w + 3360000);         //   160,000
    float4* gcb     = (float4*)(w + 3520000);         //    16,000
    float4* gnm     = (float4*)(w + 3536000);         //    16,000
    float*  gar     = (float*)(w + 3552000);          //     4,000
    int* rowcnt     = (int*)(w + 3556000);            //    40,000
    int* rowfirst   = (int*)(w + 3596000);            //    40,000
    int* rowiter    = (int*)(w + 3636000);            //    40,000
    int* prior      = (int*)(w + 3676000);            //    40,000
    int* priorcol   = (int*)(w + 3716000);            //    40,000
    int* top5       = (int*)(w + 3756000);            //    20,000
    int* dkarr      = (int*)(w + 3776000);            //     4,000
    int* colsum     = (int*)(w + 3780000);            //     4,000
    int* scal       = (int*)(w + 3784000);            //       128
    unsigned long long* pck = (unsigned long long*)(w + 3784128); // 160,000
    float* piv      = (float*)(w + 3944128);          //    80,000

    hipLaunchKernelGGL(k_prep, dim3(2701), dim3(256), 0, stream,
                       logits, pboxes, gboxes, imgw, imgh,
                       clsval, pnorm, pinfo, gcb, gnm, gar,
                       rowcnt, rowfirst, rowiter, prior, priorcol, colsum, scal);
    hipLaunchKernelGGL(k_cost2, dim3(NG), dim3(256), 0, stream,
                       pboxes, gboxes, glab, clsval, pnorm, pinfo, gcb, gnm, gar,
                       pck, piv);
    hipLaunchKernelGGL(k_costmerge, dim3(4), dim3(256), 0, stream,
                       pck, piv, rowcnt, rowfirst, rowiter, top5, dkarr);
    hipLaunchKernelGGL(k_pfixsurv, dim3(2504), dim3(256), 0, stream,
                       pboxes, gboxes, glab, clsval, pnorm, pinfo, gcb, gnm, gar,
                       prior, priorcol, colsum, rowcnt, top5, dkarr);
    for (int t = 0; t < LMAX; t++) {
        hipLaunchKernelGGL(k_iterB, dim3(NG), dim3(256), 0, stream,
                           pboxes, gboxes, glab, clsval, pnorm, pinfo, gcb, gnm, gar,
                           top5, rowiter, rowcnt, rowfirst, colsum, scal, t);
        hipLaunchKernelGGL(k_iterC, dim3(2500), dim3(256), 0, stream,
                           pboxes, gboxes, glab, clsval, pnorm, pinfo, gcb, gnm, gar,
                           prior, rowiter, priorcol, colsum, scal, t);
    }
    hipLaunchKernelGGL(k_final, dim3(40), dim3(256), 0, stream,
                       rowcnt, prior, priorcol, rowfirst, out);
}

// Round 9
// 154.987 us; speedup vs baseline: 1.0749x; 1.0749x over previous
//
#include <hip/hip_runtime.h>
#include <cfloat>
#include <cmath>

#define NP 10000
#define NG 1000
#define NC 80
#define LMAX 6
#define NCH 4
#define CHSZ (NP / NCH)     // 2500 preds per wave-task
#define WMAIN 39            // 39*64 = 2496
#define WTAIL 4             // + 4 = 2500

#define S_MULTI 12
#define S_BODY  16
#define RI_BIG  0x3fffffff
#define KMAX    0xFFFFFFFFFFFFFFFFull

// packkey(50.0f,0): strong (inb) costs < ~28, non-strong >= ~59. Gate applied
// at BLOCK (gt) scope exactly as the hardware-validated R2 chunkless kernel:
// if the gt's merged 5th-smallest candidate key >= TKEY we cannot prove the
// candidate set covers the true top-5 -> exact full rescan.
#define TKEY    0xC248000000000000ull

// per-wave candidate region (LDS ints): 4 waves x 768.
// Expected hits/wave ~100 (4% x 2500), big-gt ~500; overflow -> exact scan.
#define WCAP    768

__device__ __forceinline__ bool lexless(float av, int ai, float bv, int bi) {
    return (av < bv) || (av == bv && ai < bi);
}

// float -> order-preserving u32 (no NaNs in this data), packed with index.
// ascending u64 order == lexicographic (value asc, index asc).
__device__ __forceinline__ unsigned long long packkey(float v, int idx) {
    unsigned u = __float_as_uint(v);
    u ^= (unsigned)(((int)u) >> 31) | 0x80000000u;
    return ((unsigned long long)u << 32) | (unsigned)idx;
}
__device__ __forceinline__ int keyidx(unsigned long long k) {
    return (int)(unsigned)(k & 0xFFFFFFFFu);
}

// Exact sequential +1e5 inflation (reference adds 1e5 once per loop iter).
__device__ __forceinline__ float inflate(float c, int k) {
    for (int q = 0; q < k; q++) c += 100000.0f;
    return c;
}

// Per-pair cost+iou from precomputed tables. Contraction OFF so every kernel
// that recomputes cost(i,j) agrees bit-exactly.
__device__ __forceinline__ void cost_iou(float4 p, float4 pn, float4 pi,
        float4 g, float4 cb, float4 Gn, float ga, float clsv,
        float& cc_out, float& iou_out) {
#pragma clang fp contract(off)
    float wx = fminf(p.z, g.z) - fmaxf(p.x, g.x); wx = fmaxf(wx, 0.0f);
    float wy = fminf(p.w, g.w) - fmaxf(p.y, g.y); wy = fmaxf(wy, 0.0f);
    float inter = wx * wy;
    float uni = pi.z + ga - inter;
    float iou = inter / fmaxf(uni, 1e-12f);
    float ex = fmaxf(p.z, g.z) - fminf(p.x, g.x); ex = fmaxf(ex, 0.0f);
    float ey = fmaxf(p.w, g.w) - fminf(p.y, g.y); ey = fmaxf(ey, 0.0f);
    float enc = ex * ey;
    float giou = iou - (enc - uni) / fmaxf(enc, 1e-12f);
    float l1 = ((fabsf(pn.x - Gn.x) + fabsf(pn.y - Gn.y))
                + fabsf(pn.z - Gn.z)) + fabsf(pn.w - Gn.w);
    float cc = clsv + l1 * 5.0f;
    cc = cc + (-giou * 2.0f);
    bool inb = (pi.x > g.x && pi.x < g.z && pi.y > g.y && pi.y < g.w);
    bool inc = (pi.x > cb.x && pi.x < cb.z && pi.y > cb.y && pi.y < cb.w);
    cc = cc + ((inb && inc) ? 0.0f : 100.0f);
    cc = cc + pi.w;
    cc_out = cc; iou_out = iou;
}

// Proven per-lane sorted top-5 insertion (static indices after unroll).
__device__ __forceinline__ void ins5k(unsigned long long* kv,
        unsigned long long key) {
    if (key < kv[4]) {
        kv[4] = key;
#pragma unroll
        for (int t = 4; t > 0; t--)
            if (kv[t] < kv[t-1]) { unsigned long long tv = kv[t]; kv[t] = kv[t-1]; kv[t-1] = tv; }
    }
}
__device__ __forceinline__ void ins5i(float* iv, float iou) {
    if (iou > iv[4]) {
        iv[4] = iou;
#pragma unroll
        for (int t = 4; t > 0; t--)
            if (iv[t] > iv[t-1]) { float tv = iv[t]; iv[t] = iv[t-1]; iv[t-1] = tv; }
    }
}

// static 9-comparator sorting networks for 5 elements (constant indices only)
__device__ __forceinline__ void cswapk(unsigned long long& a,
        unsigned long long& b) {
    unsigned long long lo = (a < b) ? a : b;
    unsigned long long hi = (a < b) ? b : a;
    a = lo; b = hi;
}
__device__ __forceinline__ void sort5k(unsigned long long* a) {   // ascending
    cswapk(a[0],a[1]); cswapk(a[3],a[4]); cswapk(a[2],a[4]);
    cswapk(a[2],a[3]); cswapk(a[1],a[4]); cswapk(a[0],a[3]);
    cswapk(a[0],a[2]); cswapk(a[1],a[3]); cswapk(a[1],a[2]);
}
__device__ __forceinline__ void cswapi(float& a, float& b) {      // a=max
    float hi = fmaxf(a, b), lo = fminf(a, b);
    a = hi; b = lo;
}
__device__ __forceinline__ void sort5i(float* a) {                // descending
    cswapi(a[0],a[1]); cswapi(a[3],a[4]); cswapi(a[2],a[4]);
    cswapi(a[2],a[3]); cswapi(a[1],a[4]); cswapi(a[0],a[3]);
    cswapi(a[0],a[2]); cswapi(a[1],a[3]); cswapi(a[1],a[2]);
}

// 6-round butterfly allreduce of sorted 5-lists across the 64-lane wave
// (proven R8 on hardware). After 6 rounds every lane holds the wave's exact
// top-5 (wave-uniform); disjoint groups per round -> multiset-correct ious.
__device__ __forceinline__ void wavemerge5(unsigned long long* kv, float* iv) {
#pragma unroll
    for (int d = 1; d < 64; d <<= 1) {
        unsigned long long r0 = __shfl_xor(kv[0], d);
        unsigned long long r1 = __shfl_xor(kv[1], d);
        unsigned long long r2 = __shfl_xor(kv[2], d);
        unsigned long long r3 = __shfl_xor(kv[3], d);
        unsigned long long r4 = __shfl_xor(kv[4], d);
        kv[0] = (kv[0] < r4) ? kv[0] : r4;
        kv[1] = (kv[1] < r3) ? kv[1] : r3;
        kv[2] = (kv[2] < r2) ? kv[2] : r2;
        kv[3] = (kv[3] < r1) ? kv[3] : r1;
        kv[4] = (kv[4] < r0) ? kv[4] : r0;
        sort5k(kv);
        float s0 = __shfl_xor(iv[0], d);
        float s1 = __shfl_xor(iv[1], d);
        float s2 = __shfl_xor(iv[2], d);
        float s3 = __shfl_xor(iv[3], d);
        float s4 = __shfl_xor(iv[4], d);
        iv[0] = fmaxf(iv[0], s4);
        iv[1] = fmaxf(iv[1], s3);
        iv[2] = fmaxf(iv[2], s2);
        iv[3] = fmaxf(iv[3], s1);
        iv[4] = fmaxf(iv[4], s0);
        sort5i(iv);
    }
}

// ---------------------------------------------------------------------------
// Fused prep (verbatim R1). Block ranges:
//  [0,40): init state; [40,197): cls table; [197,201): per-gt tables;
//  [201,2701): wave-per-pred validity + per-pred tables
// ---------------------------------------------------------------------------
#define CLS_TI 64
#define PB_CLS0 40
#define PB_G0   197
#define PB_V0   201
__global__ __launch_bounds__(256) void k_prep(const float* __restrict__ logits,
        const float* __restrict__ pb, const float* __restrict__ gb,
        const int* __restrict__ imgw, const int* __restrict__ imgh,
        float* __restrict__ clsval, float4* __restrict__ pnorm,
        float4* __restrict__ pinfo, float4* __restrict__ gcb,
        float4* __restrict__ gnm, float* __restrict__ gar,
        int* rowcnt, int* rowfirst, int* rowiter, int* prior, int* priorcol,
        int* colsum, int* scal)
{
    __shared__ float sl[CLS_TI * (NC + 1)];
    int b = blockIdx.x;
    if (b < PB_CLS0) {
        int i = b * 256 + threadIdx.x;
        if (i < NP) {
            rowcnt[i] = 0; rowfirst[i] = 0x7fffffff; rowiter[i] = RI_BIG;
            prior[i] = 0; priorcol[i] = 0;
        }
        if (i < NG) colsum[i] = 0;
        if (i < 32) scal[i] = 0;
    } else if (b < PB_G0) {
        int i0 = (b - PB_CLS0) * CLS_TI;
        bool full = (i0 + CLS_TI) <= NP;
        if (full) {
            const float* src = logits + (size_t)i0 * NC;
            for (int e = threadIdx.x; e < CLS_TI * NC; e += 256) {
                int di = e / NC, c = e - di * NC;
                sl[di * (NC + 1) + c] = src[e];
            }
        } else {
            for (int e = threadIdx.x; e < CLS_TI * NC; e += 256) {
                int di = e / NC, c = e - di * NC;
                int i = i0 + di;
                sl[di * (NC + 1) + c] = (i < NP) ? logits[(size_t)i * NC + c] : 0.0f;
            }
        }
        __syncthreads();
        for (int e = threadIdx.x; e < CLS_TI * NC; e += 256) {
            int c = e >> 6, di = e & 63;
            int i = i0 + di;
            if (i >= NP) continue;
            float x = sl[di * (NC + 1) + c];
            float p = 1.0f / (1.0f + expf(-x));
            float neg = -log1pf(-(p - 1e-12f)) * 0.75f * (p * p);
            float om = 1.0f - p;
            float pos = -logf(p + 1e-12f) * 0.25f * (om * om);
            clsval[(size_t)c * NP + i] = (pos - neg) * 2.0f;   // * CLS_W
        }
    } else if (b < PB_V0) {
#pragma clang fp contract(off)
        int j = (b - PB_G0) * 256 + threadIdx.x;
        if (j < NG) {
            float fw = (float)imgw[0], fh = (float)imgh[0];
            float4 g = ((const float4*)gb)[j];
            float gcx = (g.x + g.z) * 0.5f, gcy = (g.y + g.w) * 0.5f;
            float gw = g.z - g.x, gh = g.w - g.y;
            float4 cb; cb.x = gcx - 2.5f * gw; cb.y = gcy - 2.5f * gh;
            cb.z = gcx + 2.5f * gw; cb.w = gcy + 2.5f * gh;
            gcb[j] = cb;
            float4 Gn; Gn.x = g.x / fw; Gn.y = g.y / fh; Gn.z = g.z / fw; Gn.w = g.w / fh;
            gnm[j] = Gn;
            gar[j] = (g.z - g.x) * (g.w - g.y);
        }
    } else {
#pragma clang fp contract(off)
        int wave = threadIdx.x >> 6;
        int lane = threadIdx.x & 63;
        int i = (b - PB_V0) * 4 + wave;
        if (i >= NP) return;
        float4 p = ((const float4*)pb)[i];
        float pcx = (p.x + p.z) * 0.5f, pcy = (p.y + p.w) * 0.5f;
        int vb = 0, vc = 0;
        const float4* gb4 = (const float4*)gb;
        // valid = any(inb) | any(inc): wave-level early exit as soon as
        // the disjunction is already established (~93% exit after 1 stride).
        for (int jb = 0; jb < NG; jb += 64) {
            int j = jb + lane;
            if (j < NG) {
                float4 g = gb4[j];
                vb |= (pcx > g.x && pcx < g.z && pcy > g.y && pcy < g.w) ? 1 : 0;
                float gcx = (g.x + g.z) * 0.5f, gcy = (g.y + g.w) * 0.5f;
                float gw = g.z - g.x, gh = g.w - g.y;
                vc |= (pcx > gcx - 2.5f * gw && pcx < gcx + 2.5f * gw &&
                       pcy > gcy - 2.5f * gh && pcy < gcy + 2.5f * gh) ? 1 : 0;
            }
            if (__any(vb | vc)) break;
        }
        int any = __any(vb | vc) ? 1 : 0;
        if (lane == 0) {
            float fw = (float)imgw[0], fh = (float)imgh[0];
            float4 pn; pn.x = p.x / fw; pn.y = p.y / fh; pn.z = p.z / fw; pn.w = p.w / fh;
            pnorm[i] = pn;
            float4 pi4; pi4.x = pcx; pi4.y = pcy;
            pi4.z = (p.z - p.x) * (p.w - p.y);
            pi4.w = any ? 0.0f : 10000.0f;
            pinfo[i] = pi4;
        }
    }
}

// ---------------------------------------------------------------------------
// k_cost2: block = gt j; wave = chunk wid (R8 phases 1-2 verbatim), but the
// TKEY exactness gate moves from wave/chunk scope to BLOCK/gt scope (R8
// post-mortem: ~per-chunk redos were the hidden ~3x instruction multiplier;
// a gt needs >=5 strong candidates ANYWHERE, not >=5 per chunk).
//  Phase 1: cheap overlap scan; wave-private LDS region; wave-uniform
//    register cursor (no atomics). Overflow stays WAVE-local: that wave
//    does an exact chunk scan -> its list is unconditionally exact.
//  Phase 2: dense cost_iou over the wave's region; per-lane top-5; butterfly
//    wavemerge (proven R8). IoU pads 0.0f == exact non-candidate iou.
//  Block merge: lane-0 stores wave 5-lists to LDS; thread 0 4-way merges
//    (proven costmerge logic). Gate: merged mk[4] >= TKEY -> all waves exact
//    chunk rescan + remerge (R2-validated block-scope coverage argument:
//    mk[4] < 50 < ~59 <= any non-candidate cost).
//  Epilogue (thread 0, R2-proven): dk = trunc(sum of descending merged
//    top-5 ious), top5 store, rowcnt/rowfirst/rowiter atomics.
//  k_costmerge launch eliminated.
// ---------------------------------------------------------------------------
__global__ __launch_bounds__(256) void k_cost2(
        const float* __restrict__ pb, const float* __restrict__ gb,
        const int* __restrict__ glab, const float* __restrict__ clsval,
        const float4* __restrict__ pnorm, const float4* __restrict__ pinfo,
        const float4* __restrict__ gcb, const float4* __restrict__ gnm,
        const float* __restrict__ gar,
        int* __restrict__ rowcnt, int* __restrict__ rowfirst,
        int* __restrict__ rowiter, int* __restrict__ top5,
        int* __restrict__ dkarr)
{
    __shared__ int s_list[4 * WCAP];
    __shared__ unsigned long long s_k4[4][5];
    __shared__ float s_iv4[4][5];
    __shared__ int s_redo;

    int j = blockIdx.x;
    int tid = threadIdx.x;
    int wid = tid >> 6;
    int ln  = tid & 63;
    float4 g  = ((const float4*)gb)[j];
    float4 cb = gcb[j];
    float4 Gn = gnm[j];
    float  ga = gar[j];
    const float* clscol = clsval + (size_t)glab[j] * NP;
    const float4* pb4 = (const float4*)pb;
    int base_i = wid * CHSZ;

    // ---- phase 1: overlap scan, atomic-free wave-private compaction ----
    int wbase = 0;                       // wave-uniform cursor
    for (int k = 0; k <= WMAIN; k++) {
        bool valid = (k < WMAIN) | (ln < WTAIL);
        int i = base_i + ln + k * 64;
        float4 p = pb4[valid ? i : base_i];
        bool o = valid & (p.z > g.x) & (g.z > p.x) & (p.w > g.y) & (g.w > p.y);
        unsigned long long m = __ballot(o ? 1 : 0);
        if (o) {
            int slot = wbase + __popcll(m & ((1ull << ln) - 1ull));
            if (slot < WCAP) s_list[wid * WCAP + slot] = i;
        }
        wbase += __popcll(m);
    }
    int cnt = wbase;
    bool overflow = (cnt > WCAP);        // wave-uniform

    unsigned long long kv[5]; float iv[5];
#pragma unroll
    for (int t = 0; t < 5; t++) { kv[t] = KMAX; iv[t] = overflow ? -1.0f : 0.0f; }

    if (!overflow) {
        // ---- phase 2: dense evals over the wave's candidate region ----
        for (int q = ln; q < cnt; q += 64) {
            int i = s_list[wid * WCAP + q];
            float cc, iou;
            cost_iou(pb4[i], pnorm[i], pinfo[i], g, cb, Gn, ga, clscol[i], cc, iou);
            ins5k(kv, packkey(cc, i)); ins5i(iv, iou);
        }
    } else {
        // exact chunk scan (rare: wave saw > WCAP hits); per-lane >=39 evals
        // so -1 pads never leak.
        for (int k = 0; k <= WMAIN; k++) {
            bool valid = (k < WMAIN) | (ln < WTAIL);
            if (valid) {
                int i = base_i + ln + k * 64;
                float cc, iou;
                cost_iou(pb4[i], pnorm[i], pinfo[i], g, cb, Gn, ga, clscol[i], cc, iou);
                ins5k(kv, packkey(cc, i)); ins5i(iv, iou);
            }
        }
    }
    wavemerge5(kv, iv);                  // all lanes hold wave top-5

    if (ln == 0) {
#pragma unroll
        for (int t = 0; t < 5; t++) { s_k4[wid][t] = kv[t]; s_iv4[wid][t] = iv[t]; }
    }
    __syncthreads();

    // ---- block 4-way merge (thread 0) + block-scope gate ----
    unsigned long long mk0=KMAX, mk1=KMAX, mk2=KMAX, mk3=KMAX, mk4=KMAX;
    float mi0=-2.0f, mi1=-2.0f, mi2=-2.0f, mi3=-2.0f, mi4=-2.0f;
    if (tid == 0) {
        int h0 = 0, h1 = 0, h2 = 0, h3 = 0;
        unsigned long long mk[5];
#pragma unroll
        for (int r = 0; r < 5; r++) {
            unsigned long long v0 = (h0 < 5) ? s_k4[0][h0] : KMAX;
            unsigned long long v1 = (h1 < 5) ? s_k4[1][h1] : KMAX;
            unsigned long long v2 = (h2 < 5) ? s_k4[2][h2] : KMAX;
            unsigned long long v3 = (h3 < 5) ? s_k4[3][h3] : KMAX;
            unsigned long long best = v0; int sel = 0;
            if (v1 < best) { best = v1; sel = 1; }
            if (v2 < best) { best = v2; sel = 2; }
            if (v3 < best) { best = v3; sel = 3; }
            mk[r] = best;
            h0 += (sel == 0); h1 += (sel == 1); h2 += (sel == 2); h3 += (sel == 3);
        }
        int g0 = 0, g1 = 0, g2 = 0, g3 = 0;
        float mi[5];
#pragma unroll
        for (int r = 0; r < 5; r++) {
            float w0 = (g0 < 5) ? s_iv4[0][g0] : -2.0f;
            float w1 = (g1 < 5) ? s_iv4[1][g1] : -2.0f;
            float w2 = (g2 < 5) ? s_iv4[2][g2] : -2.0f;
            float w3 = (g3 < 5) ? s_iv4[3][g3] : -2.0f;
            float best = w0; int sel = 0;
            if (w1 > best) { best = w1; sel = 1; }
            if (w2 > best) { best = w2; sel = 2; }
            if (w3 > best) { best = w3; sel = 3; }
            mi[r] = best;
            g0 += (sel == 0); g1 += (sel == 1); g2 += (sel == 2); g3 += (sel == 3);
        }
        mk0 = mk[0]; mk1 = mk[1]; mk2 = mk[2]; mk3 = mk[3]; mk4 = mk[4];
        mi0 = mi[0]; mi1 = mi[1]; mi2 = mi[2]; mi3 = mi[3]; mi4 = mi[4];
        s_redo = (mk4 >= TKEY) ? 1 : 0;
    }
    __syncthreads();

    if (s_redo) {
        // exact full rescan: every wave scans its chunk with full cost_iou
#pragma unroll
        for (int t = 0; t < 5; t++) { kv[t] = KMAX; iv[t] = -1.0f; }
        for (int k = 0; k <= WMAIN; k++) {
            bool valid = (k < WMAIN) | (ln < WTAIL);
            if (valid) {
                int i = base_i + ln + k * 64;
                float cc, iou;
                cost_iou(pb4[i], pnorm[i], pinfo[i], g, cb, Gn, ga, clscol[i], cc, iou);
                ins5k(kv, packkey(cc, i)); ins5i(iv, iou);
            }
        }
        wavemerge5(kv, iv);
        if (ln == 0) {
#pragma unroll
            for (int t = 0; t < 5; t++) { s_k4[wid][t] = kv[t]; s_iv4[wid][t] = iv[t]; }
        }
        __syncthreads();
        if (tid == 0) {
            int h0 = 0, h1 = 0, h2 = 0, h3 = 0;
            unsigned long long mk[5];
#pragma unroll
            for (int r = 0; r < 5; r++) {
                unsigned long long v0 = (h0 < 5) ? s_k4[0][h0] : KMAX;
                unsigned long long v1 = (h1 < 5) ? s_k4[1][h1] : KMAX;
                unsigned long long v2 = (h2 < 5) ? s_k4[2][h2] : KMAX;
                unsigned long long v3 = (h3 < 5) ? s_k4[3][h3] : KMAX;
                unsigned long long best = v0; int sel = 0;
                if (v1 < best) { best = v1; sel = 1; }
                if (v2 < best) { best = v2; sel = 2; }
                if (v3 < best) { best = v3; sel = 3; }
                mk[r] = best;
                h0 += (sel == 0); h1 += (sel == 1); h2 += (sel == 2); h3 += (sel == 3);
            }
            int g0 = 0, g1 = 0, g2 = 0, g3 = 0;
            float mi[5];
#pragma unroll
            for (int r = 0; r < 5; r++) {
                float w0 = (g0 < 5) ? s_iv4[0][g0] : -2.0f;
                float w1 = (g1 < 5) ? s_iv4[1][g1] : -2.0f;
                float w2 = (g2 < 5) ? s_iv4[2][g2] : -2.0f;
                float w3 = (g3 < 5) ? s_iv4[3][g3] : -2.0f;
                float best = w0; int sel = 0;
                if (w1 > best) { best = w1; sel = 1; }
                if (w2 > best) { best = w2; sel = 2; }
                if (w3 > best) { best = w3; sel = 3; }
                mi[r] = best;
                g0 += (sel == 0); g1 += (sel == 1); g2 += (sel == 2); g3 += (sel == 3);
            }
            mk0 = mk[0]; mk1 = mk[1]; mk2 = mk[2]; mk3 = mk[3]; mk4 = mk[4];
            mi0 = mi[0]; mi1 = mi[1]; mi2 = mi[2]; mi3 = mi[3]; mi4 = mi[4];
        }
    }

    // ---- folded costmerge epilogue (thread 0; R2-proven; bit-exact sum) ----
    if (tid == 0) {
        float s = (((mi0 + mi1) + mi2) + mi3) + mi4;
        int dk = (int)s;                 // astype(int32): truncation
        if (dk < 1) dk = 1;
        dkarr[j] = dk;
        int b0 = keyidx(mk0), b1 = keyidx(mk1), b2 = keyidx(mk2);
        int b3 = keyidx(mk3), b4 = keyidx(mk4);
        top5[j * 5 + 0] = b0; top5[j * 5 + 1] = b1; top5[j * 5 + 2] = b2;
        top5[j * 5 + 3] = b3; top5[j * 5 + 4] = b4;
        int bs0 = b0, bs1 = b1, bs2 = b2, bs3 = b3, bs4 = b4;
#pragma unroll
        for (int t = 0; t < 5; t++) {
            int r = (t == 0) ? bs0 : (t == 1) ? bs1 : (t == 2) ? bs2
                  : (t == 3) ? bs3 : bs4;
            if (t < dk) {
                atomicAdd(&rowcnt[r], 1);
                atomicMin(&rowfirst[r], j);
                atomicMin(&rowiter[r], -1);   // initially matched
            }
        }
    }
}

// ---------------------------------------------------------------------------
// Fused prior-detect + pfix + surv (verbatim R1).
// ---------------------------------------------------------------------------
__global__ __launch_bounds__(256) void k_pfixsurv(const float* __restrict__ pb,
        const float* __restrict__ gb, const int* __restrict__ glab,
        const float* __restrict__ clsval,
        const float4* __restrict__ pnorm, const float4* __restrict__ pinfo,
        const float4* __restrict__ gcb, const float4* __restrict__ gnm,
        const float* __restrict__ gar,
        int* __restrict__ prior, int* __restrict__ priorcol,
        int* __restrict__ colsum,
        const int* __restrict__ rowcnt, const int* __restrict__ top5,
        const int* __restrict__ dkarr)
{
    int b = blockIdx.x;
    int tid = threadIdx.x;
    if (b >= 2500) {
        int j = (b - 2500) * 256 + tid;
        if (j >= NG) return;
        int c = 0;
        int dk = dkarr[j];
        for (int t = 0; t < dk; t++) if (rowcnt[top5[j * 5 + t]] == 1) c++;
        if (c) atomicAdd(&colsum[j], c);
        return;
    }
    __shared__ float rv[256]; __shared__ int ri[256];
    for (int q = 0; q < 4; q++) {
        int row = b * 4 + q;
        if (rowcnt[row] <= 1) continue;      // uniform across block
        if (tid == 0) prior[row] = 1;
        float4 p = ((const float4*)pb)[row];
        float4 pn = pnorm[row];
        float4 pi4 = pinfo[row];
        float best = FLT_MAX; int bj = 0x7fffffff;
        for (int j = tid; j < NG; j += 256) {
            float cc, iou;
            cost_iou(p, pn, pi4, ((const float4*)gb)[j], gcb[j], gnm[j], gar[j],
                     clsval[(size_t)glab[j] * NP + row], cc, iou);
            if (lexless(cc, j, best, bj)) { best = cc; bj = j; }
        }
        rv[tid] = best; ri[tid] = bj; __syncthreads();
        for (int w = 128; w > 0; w >>= 1) {
            if (tid < w) {
                float ov = rv[tid + w]; int oi = ri[tid + w];
                if (lexless(ov, oi, rv[tid], ri[tid])) { rv[tid] = ov; ri[tid] = oi; }
            }
            __syncthreads();
        }
        if (tid == 0) {
            priorcol[row] = ri[0];
            atomicAdd(&colsum[ri[0]], 1);
        }
        __syncthreads();
    }
}

// ---------------------------------------------------------------------------
// iterB (verbatim R1): block per column; active iff colsum[j]==0.
// ---------------------------------------------------------------------------
__global__ __launch_bounds__(256) void k_iterB(const float* __restrict__ pb,
        const float* __restrict__ gb, const int* __restrict__ glab,
        const float* __restrict__ clsval,
        const float4* __restrict__ pnorm, const float4* __restrict__ pinfo,
        const float4* __restrict__ gcb, const float4* __restrict__ gnm,
        const float* __restrict__ gar, const int* __restrict__ top5,
        int* __restrict__ rowiter, int* __restrict__ rowcnt,
        int* __restrict__ rowfirst, int* __restrict__ colsum,
        int* __restrict__ scal, int t)
{
    int j = blockIdx.x;
    if (colsum[j] != 0) return;
    int tid = threadIdx.x;
    if (tid == 0) scal[S_BODY + t] = 1;

    __shared__ int s_pos;
    if (tid == 0) {
        int pos = -1;
        for (int r = 0; r < 5; r++) {
            int i = top5[j * 5 + r];
            if (rowiter[i] >= t) { pos = i; break; }
        }
        s_pos = pos;
    }
    __syncthreads();
    int pos = s_pos;

    if (pos < 0) {
        // fallback: full argmin over uninflated rows
        float4 g  = ((const float4*)gb)[j];
        float4 cb = gcb[j];
        float4 Gn = gnm[j];
        float  ga = gar[j];
        const float* clscol = clsval + (size_t)glab[j] * NP;
        const float4* pb4 = (const float4*)pb;
        __shared__ float rv[256]; __shared__ int ri[256];
        float best = FLT_MAX; int bi = 0x7fffffff;
        for (int i = tid; i < NP; i += 256) {
            if (rowiter[i] < t) continue;
            float cc, iou;
            cost_iou(pb4[i], pnorm[i], pinfo[i], g, cb, Gn, ga, clscol[i], cc, iou);
            if (lexless(cc, i, best, bi)) { best = cc; bi = i; }
        }
        rv[tid] = best; ri[tid] = bi; __syncthreads();
        for (int w = 128; w > 0; w >>= 1) {
            if (tid < w) {
                float ov = rv[tid + w]; int oi = ri[tid + w];
                if (lexless(ov, oi, rv[tid], ri[tid])) { rv[tid] = ov; ri[tid] = oi; }
            }
            __syncthreads();
        }
        pos = ri[0];
    }

    if (tid == 0) {
        colsum[j] = 1;
        int old = atomicAdd(&rowcnt[pos], 1);
        if (old >= 1) scal[S_MULTI] = 1;
        atomicMin(&rowfirst[pos], j);
        atomicMin(&rowiter[pos], t);
    }
}

// ---------------------------------------------------------------------------
// iterC (verbatim R1): iff body ran at t && anymulti: prior rows (4/block)
// re-argmin their inflated cost (exact sequential +1e5).
// ---------------------------------------------------------------------------
__global__ __launch_bounds__(256) void k_iterC(const float* __restrict__ pb,
        const float* __restrict__ gb, const int* __restrict__ glab,
        const float* __restrict__ clsval,
        const float4* __restrict__ pnorm, const float4* __restrict__ pinfo,
        const float4* __restrict__ gcb, const float4* __restrict__ gnm,
        const float* __restrict__ gar,
        const int* __restrict__ prior, const int* __restrict__ rowiter,
        int* __restrict__ priorcol, int* __restrict__ colsum,
        int* __restrict__ scal, int t)
{
    if (scal[S_BODY + t] == 0 || scal[S_MULTI] == 0) return;
    int b = blockIdx.x;
    int tid = threadIdx.x;
    __shared__ float rv[256]; __shared__ int ri[256];
    for (int q = 0; q < 4; q++) {
        int row = b * 4 + q;
        if (!prior[row]) continue;           // uniform across block
        int k = t - rowiter[row]; if (k < 0) k = 0;   // prior rows: -1 -> t+1
        float4 p = ((const float4*)pb)[row];
        float4 pn = pnorm[row];
        float4 pi4 = pinfo[row];
        float best = FLT_MAX; int bj = 0x7fffffff;
        for (int j = tid; j < NG; j += 256) {
            float cc, iou;
            cost_iou(p, pn, pi4, ((const float4*)gb)[j], gcb[j], gnm[j], gar[j],
                     clsval[(size_t)glab[j] * NP + row], cc, iou);
            float val = inflate(cc, k);
            if (lexless(val, j, best, bj)) { best = val; bj = j; }
        }
        rv[tid] = best; ri[tid] = bj; __syncthreads();
        for (int w = 128; w > 0; w >>= 1) {
            if (tid < w) {
                float ov = rv[tid + w]; int oi = ri[tid + w];
                if (lexless(ov, oi, rv[tid], ri[tid])) { rv[tid] = ov; ri[tid] = oi; }
            }
            __syncthreads();
        }
        if (tid == 0) {
            int nb = ri[0];
            int oldc = priorcol[row];
            if (nb != oldc) {
                atomicSub(&colsum[oldc], 1);
                atomicAdd(&colsum[nb], 1);
                priorcol[row] = nb;
            }
        }
        __syncthreads();
    }
}

// ---------------------------------------------------------------------------
// Final: fg = rowcnt>0; matched = priorcol (prior rows) else rowfirst. int32.
// ---------------------------------------------------------------------------
__global__ __launch_bounds__(256) void k_final(const int* __restrict__ rowcnt,
        const int* __restrict__ prior, const int* __restrict__ priorcol,
        const int* __restrict__ rowfirst, int* __restrict__ out)
{
    int i = blockIdx.x * 256 + threadIdx.x;
    if (i >= NP) return;
    int fg = rowcnt[i] > 0;
    out[i] = fg ? 1 : 0;
    out[NP + i] = fg ? (prior[i] ? priorcol[i] : rowfirst[i]) : 0;
}

extern "C" void kernel_launch(void* const* d_in, const int* in_sizes, int n_in,
                              void* d_out, int out_size, void* d_ws, size_t ws_size,
                              hipStream_t stream)
{
    (void)in_sizes; (void)n_in; (void)out_size; (void)ws_size;
    const float* logits = (const float*)d_in[0];
    const float* pboxes = (const float*)d_in[1];
    const float* gboxes = (const float*)d_in[2];
    const int*   glab   = (const int*)d_in[3];
    const int*   imgh   = (const int*)d_in[4];
    const int*   imgw   = (const int*)d_in[5];
    int* out = (int*)d_out;

    char* w = (char*)d_ws;
    float*  clsval  = (float*)(w);                    // 3,200,000
    float4* pnorm   = (float4*)(w + 3200000);         //   160,000
    float4* pinfo   = (float4*)(w + 3360000);         //   160,000
    float4* gcb     = (float4*)(w + 3520000);         //    16,000
    float4* gnm     = (float4*)(w + 3536000);         //    16,000
    float*  gar     = (float*)(w + 3552000);          //     4,000
    int* rowcnt     = (int*)(w + 3556000);            //    40,000
    int* rowfirst   = (int*)(w + 3596000);            //    40,000
    int* rowiter    = (int*)(w + 3636000);            //    40,000
    int* prior      = (int*)(w + 3676000);            //    40,000
    int* priorcol   = (int*)(w + 3716000);            //    40,000
    int* top5       = (int*)(w + 3756000);            //    20,000
    int* dkarr      = (int*)(w + 3776000);            //     4,000
    int* colsum     = (int*)(w + 3780000);            //     4,000
    int* scal       = (int*)(w + 3784000);            //       128

    hipLaunchKernelGGL(k_prep, dim3(2701), dim3(256), 0, stream,
                       logits, pboxes, gboxes, imgw, imgh,
                       clsval, pnorm, pinfo, gcb, gnm, gar,
                       rowcnt, rowfirst, rowiter, prior, priorcol, colsum, scal);
    hipLaunchKernelGGL(k_cost2, dim3(NG), dim3(256), 0, stream,
                       pboxes, gboxes, glab, clsval, pnorm, pinfo, gcb, gnm, gar,
                       rowcnt, rowfirst, rowiter, top5, dkarr);
    hipLaunchKernelGGL(k_pfixsurv, dim3(2504), dim3(256), 0, stream,
                       pboxes, gboxes, glab, clsval, pnorm, pinfo, gcb, gnm, gar,
                       prior, priorcol, colsum, rowcnt, top5, dkarr);
    for (int t = 0; t < LMAX; t++) {
        hipLaunchKernelGGL(k_iterB, dim3(NG), dim3(256), 0, stream,
                           pboxes, gboxes, glab, clsval, pnorm, pinfo, gcb, gnm, gar,
                           top5, rowiter, rowcnt, rowfirst, colsum, scal, t);
        hipLaunchKernelGGL(k_iterC, dim3(2500), dim3(256), 0, stream,
                           pboxes, gboxes, glab, clsval, pnorm, pinfo, gcb, gnm, gar,
                           prior, rowiter, priorcol, colsum, scal, t);
    }
    hipLaunchKernelGGL(k_final, dim3(40), dim3(256), 0, stream,
                       rowcnt, prior, priorcol, rowfirst, out);
}